// Round 8
// baseline (1372.255 us; speedup 1.0000x reference)
//
#include <hip/hip_runtime.h>
#include <hip/hip_fp16.h>

typedef _Float16 f16;
typedef _Float16 f16x8 __attribute__((ext_vector_type(8)));
typedef float f32x4 __attribute__((ext_vector_type(4)));

#define BB 4
#define TT 16
#define HH 64
#define WW 64
#define CC 32
#define FF 64
#define GG 256  // 4F gates

__device__ __forceinline__ float hsig(float z) {
    return fminf(fmaxf(0.2f * z + 0.5f, 0.f), 1.f);
}
__device__ __forceinline__ float tanh_fast(float x) {
    return 1.f - 2.f / (__expf(2.f * x) + 1.f);
}

// ---------------- LayerNorm over C=32: fp32 in -> fp16 out ----------------
__global__ void ln_kernel(const float* __restrict__ x,
                          const float* __restrict__ gamma,
                          const float* __restrict__ beta,
                          f16* __restrict__ xn) {
    __shared__ float sg[CC], sb[CC];
    if (threadIdx.x < CC) sg[threadIdx.x] = gamma[threadIdx.x];
    else if (threadIdx.x < 2 * CC) sb[threadIdx.x - CC] = beta[threadIdx.x - CC];
    __syncthreads();
    int q = blockIdx.x * 256 + threadIdx.x;  // pixel < B*T*H*W = 262144
    const float* xp = x + (size_t)q * CC;
    float v[CC];
    float s = 0.f, s2 = 0.f;
#pragma unroll
    for (int c = 0; c < CC; c += 4) {
        float4 t4 = *(const float4*)(xp + c);
        v[c] = t4.x; v[c + 1] = t4.y; v[c + 2] = t4.z; v[c + 3] = t4.w;
        s += t4.x + t4.y + t4.z + t4.w;
        s2 += t4.x * t4.x + t4.y * t4.y + t4.z * t4.z + t4.w * t4.w;
    }
    float mu = s * (1.f / CC);
    float var = s2 * (1.f / CC) - mu * mu;
    float rs = rsqrtf(var + 1e-3f);
    f16 o[CC];
#pragma unroll
    for (int c = 0; c < CC; c++)
        o[c] = (f16)((v[c] - mu) * rs * sg[c] + sb[c]);
    f16x8* d = (f16x8*)(xn + (size_t)q * CC);
#pragma unroll
    for (int c = 0; c < 4; c++) d[c] = *(f16x8*)&o[c * 8];
}

// ------- Weight transpose: wcat[g][0..288)=Wx taps, [288..864)=Wh taps (k contig) -------
__global__ void wprep_kernel(const float* __restrict__ wx, const float* __restrict__ wh,
                             f16* __restrict__ wcat) {
    int e = blockIdx.x * 256 + threadIdx.x;
    if (e < 9 * CC * GG) {                    // 73728: Wx [tap][c][g] -> [g][tap*32+c]
        int g = e & 255, k = e >> 8;
        wcat[g * 864 + k] = (f16)wx[e];
    } else {
        e -= 9 * CC * GG;
        if (e < 9 * FF * GG) {                // 147456: Wh [tap][f][g] -> [g][288+tap*64+f]
            int g = e & 255, k = e >> 8;
            wcat[g * 864 + 288 + k] = (f16)wh[e];
        }
    }
}

// ---------------- Persistent fused ConvLSTM: all 16 steps, one launch ----------------
// Grid: 512 = 256 px-tiles x 2 gate-halves. Block: 128 (2 waves), LDS 27.5KB ->
// residency >= 2 blocks/CU guaranteed. Wave w = fch-16-half; wave tile 64px x 64g
// (4 M x 4 cls, acc[4][4]). B-frags streamed L2->VGPR (compile-time chunk offsets),
// A-frags from LDS patches, barrier-free K-loop (R6-proven). c-state in 16 VGPRs for
// all 16 steps. Grid barrier: threadfence+relaxed add arrival; RELAXED polls (no cache
// inv per poll!) + one ACQUIRE after the generation flips.
__global__ __launch_bounds__(128)
void lstm_kernel(const f16* __restrict__ xn, const f16* __restrict__ wcat,
                 const float* __restrict__ bs, f16* __restrict__ hs,
                 float* __restrict__ out, unsigned* __restrict__ bar) {
    __shared__ __align__(16) f16 xpatch[100 * 40];   //  8.0 KB (stride 40)
    __shared__ __align__(16) f16 hpatch[100 * 72];   // 14.4 KB (stride 72)
    __shared__ __align__(16) f16 hstage[64 * 40];    //  5.1 KB (stride 40)

    int tile = blockIdx.x >> 1, nhalf = blockIdx.x & 1;
    int bb = tile >> 6, ty = (tile >> 3) & 7, tx = tile & 7;
    int tid = threadIdx.x;
    int lane = tid & 63, w = tid >> 6;
    int quad = lane >> 4, noff = lane & 15;

    int fch = (nhalf << 5) + (w << 4) + noff;  // f-channel in [0,64)
    float b_i = bs[fch], b_f = bs[64 + fch], b_c = bs[128 + fch], b_o = bs[192 + fch];

    // B-frag base pointers (chunk offsets become compile-time immediates)
    const f16* bbase[4];
#pragma unroll
    for (int cls = 0; cls < 4; cls++)
        bbase[cls] = wcat + (size_t)((cls << 6) + fch) * 864 + (quad << 3);

    int ab[4];
#pragma unroll
    for (int mt = 0; mt < 4; mt++) {
        int m = (mt << 4) + noff;
        ab[mt] = (m >> 3) * 10 + (m & 7);
    }

    // c-state register-resident for all 16 steps
    f32x4 cs[4];
#pragma unroll
    for (int j = 0; j < 4; j++) cs[j] = (f32x4){0.f, 0.f, 0.f, 0.f};

    f16x8 zv = {0, 0, 0, 0, 0, 0, 0, 0};

    // stage xpatch for t=0
    {
        const f16* xslice = xn + (size_t)(bb * TT) * (HH * WW) * CC;
        for (int j = tid; j < 200; j += 128) {
            int pix = j >> 1, part = j & 1;
            int py = pix / 10, px = pix % 10;
            int y = ty * 8 - 1 + py, x = tx * 8 - 1 + px;
            f16x8* d = (f16x8*)&xpatch[pix * 40 + part * 16];
            if (y >= 0 && y < HH && x >= 0 && x < WW) {
                const f16x8* s = (const f16x8*)(xslice + ((size_t)y * WW + x) * CC + part * 16);
                d[0] = s[0]; d[1] = s[1];
            } else { d[0] = zv; d[1] = zv; }
        }
    }

    for (int t = 0; t < TT; t++) {
        int rslot = t & 1;
        const f16* hr = hs + (size_t)rslot * (BB * HH * WW * FF);
        f16* hw = hs + (size_t)(1 - rslot) * (BB * HH * WW * FF);

        // stage hpatch (fresh post-acquire reads)
        for (int j = tid; j < 200; j += 128) {
            int pix = j >> 1, part = j & 1;
            int py = pix / 10, px = pix % 10;
            int y = ty * 8 - 1 + py, x = tx * 8 - 1 + px;
            f16x8* d = (f16x8*)&hpatch[pix * 72 + part * 32];
            if (y >= 0 && y < HH && x >= 0 && x < WW) {
                const f16x8* s = (const f16x8*)(hr + ((size_t)(bb * HH + y) * WW + x) * FF + part * 32);
                d[0] = s[0]; d[1] = s[1]; d[2] = s[2]; d[3] = s[3];
            } else { d[0] = zv; d[1] = zv; d[2] = zv; d[3] = zv; }
        }

        f32x4 acc[4][4];
#pragma unroll
        for (int i = 0; i < 4; i++)
#pragma unroll
            for (int j = 0; j < 4; j++) acc[i][j] = (f32x4){0.f, 0.f, 0.f, 0.f};

        __syncthreads();  // patches ready

        // ---- barrier-free K-loop: 27 chunks, B streamed from L2 ----
#pragma unroll
        for (int c = 0; c < 27; c++) {
            const bool isx = c < 9;
            const int tap = isx ? c : ((c - 9) >> 1);
            const int coff = isx ? 0 : (((c - 9) & 1) << 5);
            const int dy = tap / 3, dx = tap % 3;
            const f16* ap = isx ? xpatch : hpatch;
            const int stride = isx ? 40 : 72;
            f16x8 bf[4], a[4];
#pragma unroll
            for (int cls = 0; cls < 4; cls++) bf[cls] = *(const f16x8*)(bbase[cls] + c * 32);
#pragma unroll
            for (int mt = 0; mt < 4; mt++)
                a[mt] = *(const f16x8*)&ap[(ab[mt] + dy * 10 + dx) * stride + coff + (quad << 3)];
#pragma unroll
            for (int cls = 0; cls < 4; cls++)
#pragma unroll
                for (int mt = 0; mt < 4; mt++)
                    acc[mt][cls] = __builtin_amdgcn_mfma_f32_16x16x32_f16(a[mt], bf[cls], acc[mt][cls], 0, 0, 0);
        }

        __syncthreads();  // all patch reads done (xpatch about to be overwritten)

        // stage xpatch for t+1 now: overlaps epilogue + barrier wait
        if (t < TT - 1) {
            const f16* xslice = xn + (size_t)(bb * TT + t + 1) * (HH * WW) * CC;
            for (int j = tid; j < 200; j += 128) {
                int pix = j >> 1, part = j & 1;
                int py = pix / 10, px = pix % 10;
                int y = ty * 8 - 1 + py, x = tx * 8 - 1 + px;
                f16x8* d = (f16x8*)&xpatch[pix * 40 + part * 16];
                if (y >= 0 && y < HH && x >= 0 && x < WW) {
                    const f16x8* s = (const f16x8*)(xslice + ((size_t)y * WW + x) * CC + part * 16);
                    d[0] = s[0]; d[1] = s[1];
                } else { d[0] = zv; d[1] = zv; }
            }
        }

        // ---- epilogue: gates + state (c in registers); h -> hstage ----
        int fchL = (w << 4) + noff;
#pragma unroll
        for (int mt = 0; mt < 4; mt++) {
#pragma unroll
            for (int r = 0; r < 4; r++) {
                int m = (mt << 4) + (quad << 2) + r;  // C/D row = quad*4+reg
                float zi = acc[mt][0][r] + b_i;
                float zf = acc[mt][1][r] + b_f;
                float zc = acc[mt][2][r] + b_c;
                float zo = acc[mt][3][r] + b_o;
                float ig = hsig(zi), fg = hsig(zf), og = hsig(zo);
                float cn = fg * cs[mt][r] + ig * tanh_fast(zc);
                cs[mt][r] = cn;
                hstage[m * 40 + fchL] = (f16)(og * tanh_fast(cn));
            }
        }
        __syncthreads();  // hstage + xpatch(t+1) writes complete

        // coalesced h write: 64 px x 32 f16 (this block's gate-half)
        {
            int px = tid >> 1, part = tid & 1;
            int y = ty * 8 + (px >> 3), x = tx * 8 + (px & 7);
            const f16x8* s = (const f16x8*)&hstage[px * 40 + part * 16];
            f16x8* d = (f16x8*)(hw + ((size_t)(bb * HH + y) * WW + x) * FF + (nhalf << 5) + part * 16);
            d[0] = s[0]; d[1] = s[1];
        }
        // fused 2x2 maxpool: 16 out px x 32 fch -> fp32 out
        {
            int opx = tid >> 3, fp = (tid & 7) * 4;
            int oy2 = opx >> 2, ox2 = opx & 3;
            int p00 = (oy2 * 2) * 8 + ox2 * 2;
            float4 mv;
            float* mp = (float*)&mv;
#pragma unroll
            for (int r = 0; r < 4; r++) {
                mp[r] = fmaxf(fmaxf((float)hstage[p00 * 40 + fp + r], (float)hstage[(p00 + 1) * 40 + fp + r]),
                              fmaxf((float)hstage[(p00 + 8) * 40 + fp + r], (float)hstage[(p00 + 9) * 40 + fp + r]));
            }
            size_t oidx = ((size_t)((bb * TT + t) * 32 + ty * 4 + oy2) * 32 + tx * 4 + ox2) * 64
                        + (nhalf << 5) + fp;
            *(float4*)(out + oidx) = mv;
        }

        // ---- grid barrier (not after the last step) ----
        if (t < TT - 1) {
            __threadfence();   // release h-writes of ALL threads (once per step)
            __syncthreads();
            if (tid == 0) {
                unsigned gen = __hip_atomic_load(&bar[1], __ATOMIC_RELAXED, __HIP_MEMORY_SCOPE_AGENT);
                unsigned a = __hip_atomic_fetch_add(&bar[0], 1u, __ATOMIC_RELAXED, __HIP_MEMORY_SCOPE_AGENT);
                if (a == gridDim.x - 1) {
                    __hip_atomic_store(&bar[0], 0u, __ATOMIC_RELAXED, __HIP_MEMORY_SCOPE_AGENT);
                    __hip_atomic_store(&bar[1], gen + 1u, __ATOMIC_RELEASE, __HIP_MEMORY_SCOPE_AGENT);
                } else {
                    // RELAXED polling: no cache invalidation per iteration
                    while (__hip_atomic_load(&bar[1], __ATOMIC_RELAXED, __HIP_MEMORY_SCOPE_AGENT) == gen)
                        __builtin_amdgcn_s_sleep(8);
                }
                // exactly ONE acquire to pull in remote h-writes
                (void)__hip_atomic_load(&bar[1], __ATOMIC_ACQUIRE, __HIP_MEMORY_SCOPE_AGENT);
            }
            __syncthreads();
        }
    }
}

extern "C" void kernel_launch(void* const* d_in, const int* in_sizes, int n_in,
                              void* d_out, int out_size, void* d_ws, size_t ws_size,
                              hipStream_t stream) {
    const float* x = (const float*)d_in[0];
    const float* gamma = (const float*)d_in[1];
    const float* beta = (const float*)d_in[2];
    const float* wx = (const float*)d_in[3];
    const float* wh = (const float*)d_in[4];
    const float* bs = (const float*)d_in[5];
    float* out = (float*)d_out;

    // workspace layout (16B-aligned); ~21.5 MB
    char* ws = (char*)d_ws;
    f16* xn = (f16*)ws;                        // 16,777,216 B
    f16* wcat = (f16*)(ws + 16777216);         // 256*864*2 = 442,368 B
    f16* hs = (f16*)(ws + 17219584);           // 2 x 2,097,152 B (ping-pong)
    unsigned* bar = (unsigned*)(ws + 21413888);  // 8 B barrier state

    hipMemsetAsync(hs, 0, (size_t)BB * HH * WW * FF * 2, stream);  // h0 = 0 (slot 0)
    hipMemsetAsync(bar, 0, 8, stream);                             // barrier reset

    ln_kernel<<<1024, 256, 0, stream>>>(x, gamma, beta, xn);
    wprep_kernel<<<864, 256, 0, stream>>>(wx, wh, wcat);
    lstm_kernel<<<512, 128, 0, stream>>>(xn, wcat, bs, hs, out, bar);
}